// Round 5
// baseline (537.771 us; speedup 1.0000x reference)
//
#include <hip/hip_runtime.h>

#define N_NODES 100000
#define E_EDGES 1600000
#define EP (E_EDGES + N_NODES)
#define NG 1024
#define NEG 0.2f
#define EPS_BN 1e-5f

#define NB 196        // dst buckets of 512 nodes
#define BCAP 12288    // per-bucket capacity
#define GRID_AGG 1536

typedef __attribute__((ext_vector_type(8))) short bf8_t;
typedef __attribute__((ext_vector_type(4))) float f4_t;

__device__ __forceinline__ unsigned short f2b(float f) {   // f32 -> bf16 RNE
    unsigned u = __float_as_uint(f);
    u += 0x7FFF + ((u >> 16) & 1);
    return (unsigned short)(u >> 16);
}

// 16-lane (DPP row) sum, result broadcast to all 16 lanes. Fused add+rotate,
// s_nop 1 guards the VALU-write -> DPP-read-src0 hazard (asm bypasses compiler
// hazard tracking).
__device__ __forceinline__ float rsum16(float p) {
    float t;
    asm volatile("s_nop 1\n\tv_add_f32_dpp %0, %1, %1 row_ror:8 row_mask:0xf bank_mask:0xf"
                 : "=&v"(t) : "v"(p));
    asm volatile("s_nop 1\n\tv_add_f32_dpp %0, %1, %1 row_ror:4 row_mask:0xf bank_mask:0xf"
                 : "=&v"(p) : "v"(t));
    asm volatile("s_nop 1\n\tv_add_f32_dpp %0, %1, %1 row_ror:2 row_mask:0xf bank_mask:0xf"
                 : "=&v"(t) : "v"(p));
    asm volatile("s_nop 1\n\tv_add_f32_dpp %0, %1, %1 row_ror:1 row_mask:0xf bank_mask:0xf"
                 : "=&v"(p) : "v"(t));
    return p;
}

// ================= CSR build: partition -> histogram -> scan -> place =======
__global__ __launch_bounds__(256) void k_part(const int* __restrict__ ei,
                                              int* __restrict__ bucketCur,
                                              int2* __restrict__ buf) {
    __shared__ int lh[NB], lb[NB];
    int t = threadIdx.x;
    for (int i = t; i < NB; i += 256) lh[i] = 0;
    __syncthreads();
    int base = blockIdx.x * 4096;
    int2 e[16];
    int rk[16];
#pragma unroll
    for (int i = 0; i < 16; i++) {
        int idx = base + i * 256 + t;
        int s, d;
        if (idx < E_EDGES) { s = ei[idx]; d = ei[E_EDGES + idx]; }
        else if (idx < EP) { s = d = idx - E_EDGES; }
        else { s = -1; d = -1; }
        e[i].x = s; e[i].y = d;
        rk[i] = (d >= 0) ? atomicAdd(&lh[d >> 9], 1) : 0;
    }
    __syncthreads();
    for (int i = t; i < NB; i += 256) lb[i] = atomicAdd(&bucketCur[i], lh[i]);
    __syncthreads();
#pragma unroll
    for (int i = 0; i < 16; i++) {
        int d = e[i].y;
        if (d >= 0) {
            int bkt = d >> 9;
            buf[(size_t)bkt * BCAP + lb[bkt] + rk[i]] = e[i];
        }
    }
}

__global__ __launch_bounds__(256) void k_build_a(const int2* __restrict__ buf,
                                                 const int* __restrict__ bcnt,
                                                 int* __restrict__ cnt) {
    __shared__ int h[512];
    int b = blockIdx.x, t = threadIdx.x;
    for (int i = t; i < 512; i += 256) h[i] = 0;
    __syncthreads();
    int n = bcnt[b];
    const int2* p = buf + (size_t)b * BCAP;
    for (int i = t; i < n; i += 256) atomicAdd(&h[p[i].y & 511], 1);
    __syncthreads();
    int base = b << 9;
    for (int i = t; i < 512; i += 256) {
        int d = base + i;
        if (d < N_NODES) cnt[d] = h[i];
    }
}

__global__ __launch_bounds__(256) void k_s1(const int* __restrict__ cnt,
                                            int* __restrict__ bsum) {
    int b = blockIdx.x, t = threadIdx.x;
    int idx = b * 256 + t;
    int v = (idx < N_NODES) ? cnt[idx] : 0;
#pragma unroll
    for (int o = 1; o < 64; o <<= 1) v += __shfl_xor(v, o, 64);
    __shared__ int ws[4];
    if ((t & 63) == 0) ws[t >> 6] = v;
    __syncthreads();
    if (t == 0) bsum[b] = ws[0] + ws[1] + ws[2] + ws[3];
}

__global__ __launch_bounds__(512) void k_s2(const int* __restrict__ bsum,
                                            int* __restrict__ bbase,
                                            int* __restrict__ startA) {
    __shared__ int s[512];
    int t = threadIdx.x;
    int v = (t < 391) ? bsum[t] : 0;
    s[t] = v;
    __syncthreads();
    for (int o = 1; o < 512; o <<= 1) {
        int u = (t >= o) ? s[t - o] : 0;
        __syncthreads();
        s[t] += u;
        __syncthreads();
    }
    if (t < 391) bbase[t] = s[t] - v;   // exclusive
    if (t == 0) startA[N_NODES] = EP;
}

__global__ __launch_bounds__(256) void k_s3(const int* __restrict__ cnt,
                                            const int* __restrict__ bbase,
                                            int* __restrict__ startA) {
    __shared__ int s[256];
    int b = blockIdx.x, t = threadIdx.x;
    int idx = b * 256 + t;
    int v = (idx < N_NODES) ? cnt[idx] : 0;
    s[t] = v;
    __syncthreads();
    for (int o = 1; o < 256; o <<= 1) {
        int u = (t >= o) ? s[t - o] : 0;
        __syncthreads();
        s[t] += u;
        __syncthreads();
    }
    if (idx < N_NODES) startA[idx] = bbase[b] + s[t] - v;
}

// colA entries stored as BYTE offsets (src * 256) for saddr-form gathers.
__global__ __launch_bounds__(256) void k_build_b(const int2* __restrict__ buf,
                                                 const int* __restrict__ bcnt,
                                                 const int* __restrict__ startA,
                                                 int* __restrict__ colA) {
    __shared__ int h[512];
    int b = blockIdx.x, t = threadIdx.x;
    for (int i = t; i < 512; i += 256) h[i] = 0;
    __syncthreads();
    int n = bcnt[b];
    const int2* p = buf + (size_t)b * BCAP;
    for (int i = t; i < n; i += 256) {
        int2 e = p[i];
        int r = atomicAdd(&h[e.y & 511], 1);
        colA[startA[e.y] + r] = e.x << 8;
    }
}

// ================= W preconvert: f32 [k][n] -> bf16 swizzled LDS image ======
__global__ void k_wconv(const float* __restrict__ Wl, const float* __restrict__ Wr,
                        unsigned short* __restrict__ img) {
    int g = blockIdx.x * 256 + threadIdx.x;   // 4096 chunks
    int m = g >> 11, n = (g >> 4) & 127, kb = g & 15;
    const float* W = m ? Wr : Wl;
    unsigned short v[8];
#pragma unroll
    for (int j = 0; j < 8; j++) v[j] = f2b(W[(kb * 8 + j) * 128 + n]);
    int off = ((n * 256 + kb * 16) ^ ((n & 7) << 4)) + m * 32768;
    *(int4*)((char*)img + off) = *(int4*)v;
}

// ================= MFMA dual GEMM: xl = A@Wl + bl, xr = A@Wr + br (bf16) =====
template<bool AFF, bool BF16IN>
__global__ __launch_bounds__(256) void k_gemm(
    const void* __restrict__ Ain, const unsigned short* __restrict__ Wimg,
    const float* __restrict__ bl, const float* __restrict__ br,
    const float* __restrict__ sc, const float* __restrict__ sh,
    unsigned short* __restrict__ xl, unsigned short* __restrict__ xr, int M)
{
    __shared__ char lds[81920];
    short* As = (short*)lds;             // 16384 B
    short* Wt = (short*)(lds + 16384);   // 65536 B

    int t = threadIdx.x;
    int lane = t & 63;
    int w = t >> 6;
    int brow = blockIdx.x * 64;

    // ---- stage W: linear 64KB copy (image pre-swizzled by k_wconv) ----
    {
        const int4* src = (const int4*)Wimg;
        int4* dst = (int4*)Wt;
#pragma unroll
        for (int r = 0; r < 16; ++r) dst[r * 256 + t] = src[r * 256 + t];
    }

    // ---- stage A (f32 or packed-bf16 input; optional BN-affine+relu) ----
    {
        int kbase = (t & 7) * 16;
        float scv[16], shv[16];
        if (AFF) {
#pragma unroll
            for (int q = 0; q < 4; ++q) {
                float4 a4 = *(const float4*)&sc[kbase + q * 4];
                float4 b4 = *(const float4*)&sh[kbase + q * 4];
                scv[q*4+0]=a4.x; scv[q*4+1]=a4.y; scv[q*4+2]=a4.z; scv[q*4+3]=a4.w;
                shv[q*4+0]=b4.x; shv[q*4+1]=b4.y; shv[q*4+2]=b4.z; shv[q*4+3]=b4.w;
            }
        }
#pragma unroll
        for (int p = 0; p < 2; ++p) {
            int row = p * 32 + (t >> 3);
            int ar = brow + row; if (ar >= M) ar = M - 1;
            unsigned short vb[16];
            if (BF16IN) {
                const unsigned* src = (const unsigned*)Ain + (size_t)ar * 64 + (kbase >> 1);
                int4 r0 = *(const int4*)src;
                int4 r1 = *(const int4*)(src + 4);
                unsigned ua[8] = {(unsigned)r0.x,(unsigned)r0.y,(unsigned)r0.z,(unsigned)r0.w,
                                  (unsigned)r1.x,(unsigned)r1.y,(unsigned)r1.z,(unsigned)r1.w};
#pragma unroll
                for (int m = 0; m < 8; ++m) {
                    float f0 = __uint_as_float(ua[m] << 16);
                    float f1 = __uint_as_float(ua[m] & 0xFFFF0000u);
                    if (AFF) {
                        f0 = fmaxf(fmaf(f0, scv[2*m], shv[2*m]), 0.f);
                        f1 = fmaxf(fmaf(f1, scv[2*m+1], shv[2*m+1]), 0.f);
                    }
                    vb[2*m] = f2b(f0); vb[2*m+1] = f2b(f1);
                }
            } else {
                const float* src = (const float*)Ain + (size_t)ar * 128 + kbase;
#pragma unroll
                for (int q = 0; q < 4; ++q) {
                    float4 x4 = *(const float4*)&src[q * 4];
                    float vv[4] = {x4.x, x4.y, x4.z, x4.w};
#pragma unroll
                    for (int e = 0; e < 4; ++e) {
                        float f = vv[e];
                        if (AFF) f = fmaxf(fmaf(f, scv[q*4+e], shv[q*4+e]), 0.f);
                        vb[q * 4 + e] = f2b(f);
                    }
                }
            }
            int swz = (row & 7) << 4;
#pragma unroll
            for (int u = 0; u < 2; ++u) {
                int off = (row * 256 + kbase * 2 + u * 16) ^ swz;
                *(int4*)((char*)As + off) = *(int4*)&vb[u * 8];
            }
        }
    }
    __syncthreads();

    // ---- compute ----
    int rl = lane & 15;
    int kh = lane >> 4;
    int mat = w >> 1;
    int c0 = (w & 1) * 64;
    int swz = (rl & 7) << 4;

    f4_t acc[4][4];
#pragma unroll
    for (int i = 0; i < 4; ++i)
#pragma unroll
        for (int j = 0; j < 4; ++j) { f4_t z = {0.f,0.f,0.f,0.f}; acc[i][j] = z; }

    const char* Asc = (const char*)As;
    const char* Wtc = (const char*)Wt + mat * 32768;

#pragma unroll
    for (int s = 0; s < 4; ++s) {
        int kb2 = (s * 32 + kh * 8) * 2;
        bf8_t af[4], bfr[4];
#pragma unroll
        for (int i = 0; i < 4; ++i) {
            int row = 16 * i + rl;
            af[i] = *(const bf8_t*)(Asc + ((row * 256 + kb2) ^ swz));
        }
#pragma unroll
        for (int j = 0; j < 4; ++j) {
            int n = c0 + 16 * j + rl;
            bfr[j] = *(const bf8_t*)(Wtc + ((n * 256 + kb2) ^ swz));
        }
#pragma unroll
        for (int i = 0; i < 4; ++i)
#pragma unroll
            for (int j = 0; j < 4; ++j)
                acc[i][j] = __builtin_amdgcn_mfma_f32_16x16x32_bf16(af[i], bfr[j], acc[i][j], 0, 0, 0);
    }

    // ---- epilogue: bias + bf16, bounce through LDS for coalesced stores ----
    __syncthreads();
    short* Cs = (short*)lds;   // [64][256] bf16, swizzled
    const float* bb = mat ? br : bl;
    float blv[4];
#pragma unroll
    for (int j = 0; j < 4; ++j) blv[j] = bb[c0 + 16 * j + rl];
    int colbase = mat * 128 + c0;
#pragma unroll
    for (int i = 0; i < 4; ++i)
#pragma unroll
        for (int j = 0; j < 4; ++j) {
            int col = colbase + 16 * j + rl;
#pragma unroll
            for (int q = 0; q < 4; ++q) {
                int row = 16 * i + kh * 4 + q;
                int off = (row * 512 + col * 2) ^ ((row & 7) << 4);
                *(short*)((char*)Cs + off) = (short)f2b(acc[i][j][q] + blv[j]);
            }
        }
    __syncthreads();
#pragma unroll
    for (int rep = 0; rep < 8; ++rep) {
        int unit = rep * 256 + t;
        int row = unit >> 5;
        int slot = unit & 31;
        int gr = brow + row;
        if (gr < M) {
            int off = (row * 512 + slot * 16) ^ ((row & 7) << 4);
            int4 vv = *(const int4*)((char*)Cs + off);
            unsigned short* O = (slot < 16) ? xl : xr;
            int gcol = (slot & 15) * 8;
            *(int4*)&O[(size_t)gr * 128 + gcol] = vv;
        }
    }
}

// ===== fused edge softmax + aggregation + BN-stats (bf16 in/out, DPP reduce) =
__global__ __launch_bounds__(256) void k_agg(
    const unsigned* __restrict__ xl, const unsigned* __restrict__ xr,
    const int* __restrict__ startA, const unsigned* __restrict__ colB,
    const float* __restrict__ att, const float* __restrict__ bias,
    unsigned* __restrict__ hout, float* __restrict__ gsum, float* __restrict__ gsq)
{
    int t = threadIdx.x;
    int wave = t >> 6, lane = t & 63;
    int c0 = lane * 2;
    unsigned lane4 = (unsigned)lane * 4u;
    const char* xlb = (const char*)xl;

    float att0 = att[c0], att1 = att[c0 + 1];
    float b0 = bias[c0], b1 = bias[c0 + 1];

    float s0 = 0.f, s1 = 0.f, q0 = 0.f, q1 = 0.f;

    for (int n = blockIdx.x * 4 + wave; n < N_NODES; n += 4 * GRID_AGG) {
        unsigned uxr = xr[(size_t)n * 64 + lane];
        float xr0 = __uint_as_float(uxr << 16);
        float xr1 = __uint_as_float(uxr & 0xFFFF0000u);
        int a0i = startA[n];
        int cn = startA[n + 1] - a0i;   // >= 1 (self loop)

        float acc0 = 0.f, acc1 = 0.f, wsum = 0.f;
        unsigned myS = (lane < cn) ? colB[a0i + lane] : 0u;

#define LDROW(J) (*(const unsigned*)(xlb + (unsigned)__shfl((int)myS, (J) & 63, 64) + lane4))
        unsigned u0 = LDROW(0);
        unsigned u1 = (cn > 1) ? LDROW(1) : u0;
        unsigned u2 = (cn > 2) ? LDROW(2) : u0;
        unsigned u3 = (cn > 3) ? LDROW(3) : u0;

        for (int j = 0; j < cn; ++j) {
            unsigned un = u3;
            int jn = j + 4;
            if (jn < cn) {
                if ((jn & 63) == 0)
                    myS = (jn + lane < cn) ? colB[a0i + jn + lane] : 0u;
                un = LDROW(jn);
            }
            float v0 = __uint_as_float(u0 << 16);
            float v1 = __uint_as_float(u0 & 0xFFFF0000u);
            float e0 = v0 + xr0, e1 = v1 + xr1;
            e0 = fmaxf(e0, 0.2f * e0);          // leaky relu (NEG=0.2)
            e1 = fmaxf(e1, 0.2f * e1);
            float p = fmaf(e0, att0, e1 * att1);
            p = rsum16(p);                       // per-head sum, bcast to 16 lanes
            float wg = __expf(p);
            acc0 = fmaf(wg, v0, acc0);
            acc1 = fmaf(wg, v1, acc1);
            wsum += wg;
            u0 = u1; u1 = u2; u2 = u3; u3 = un;
        }
#undef LDROW
        float inv = 1.f / wsum;
        float o0 = fmaf(acc0, inv, b0);
        float o1 = fmaf(acc1, inv, b1);
        s0 += o0; q0 = fmaf(o0, o0, q0);
        s1 += o1; q1 = fmaf(o1, o1, q1);
        hout[(size_t)n * 64 + lane] = (unsigned)f2b(o0) | ((unsigned)f2b(o1) << 16);
    }

    // cross-wave BN-stat reduce (lane == channel pair across all waves)
    __shared__ float2 sS[4][64], sQ[4][64];
    sS[wave][lane] = make_float2(s0, s1);
    sQ[wave][lane] = make_float2(q0, q1);
    __syncthreads();
    if (t < 64) {
        float2 A0 = sS[0][t], A1 = sS[1][t], A2 = sS[2][t], A3 = sS[3][t];
        float2 B0 = sQ[0][t], B1 = sQ[1][t], B2 = sQ[2][t], B3 = sQ[3][t];
        atomicAdd(&gsum[2 * t],     A0.x + A1.x + A2.x + A3.x);
        atomicAdd(&gsum[2 * t + 1], A0.y + A1.y + A2.y + A3.y);
        atomicAdd(&gsq[2 * t],      B0.x + B1.x + B2.x + B3.x);
        atomicAdd(&gsq[2 * t + 1],  B0.y + B1.y + B2.y + B3.y);
    }
}

// ================= BN finalize ==============================================
__global__ void k_bnfinal(const float* __restrict__ gsum, const float* __restrict__ gsq,
                          const float* __restrict__ g, const float* __restrict__ be,
                          float* __restrict__ sc, float* __restrict__ sh) {
    int c = threadIdx.x;   // 128
    float mu = gsum[c] * (1.f / N_NODES);
    float var = gsq[c] * (1.f / N_NODES) - mu * mu;
    float s = rsqrtf(var + EPS_BN) * g[c];
    sc[c] = s;
    sh[c] = be[c] - mu * s;
}

// ================= graph boundaries (batch is sorted) ========================
__global__ void k_gstart(const int* __restrict__ batch, int* __restrict__ gstart) {
    int i = blockIdx.x * 256 + threadIdx.x;
    if (i >= N_NODES) return;
    int b = batch[i];
    int prev = (i == 0) ? -1 : batch[i - 1];
    for (int g = prev + 1; g <= b; g++) gstart[g] = i;
    if (i == N_NODES - 1)
        for (int g = b + 1; g <= NG; g++) gstart[g] = N_NODES;
}

// ====== mean pool over bf16 h (fused BN2 affine+relu) + concat global =======
__global__ __launch_bounds__(256) void k_pool(const unsigned* __restrict__ h,
                                              const int* __restrict__ gstart,
                                              const float* __restrict__ gf,
                                              const float* __restrict__ sc,
                                              const float* __restrict__ sh,
                                              float* __restrict__ z) {
    int wave = threadIdx.x >> 6;
    int lane = threadIdx.x & 63;
    int g = blockIdx.x * 4 + wave;
    if (g >= NG) return;
    int c0 = lane * 2;
    float sc0 = sc[c0], sc1 = sc[c0 + 1], sh0 = sh[c0], sh1 = sh[c0 + 1];
    int r0 = gstart[g], r1 = gstart[g + 1];
    float s0 = 0.f, s1 = 0.f;
    for (int r = r0; r < r1; r++) {
        unsigned u = h[(size_t)r * 64 + lane];
        float v0 = __uint_as_float(u << 16);
        float v1 = __uint_as_float(u & 0xFFFF0000u);
        s0 += fmaxf(fmaf(v0, sc0, sh0), 0.f);
        s1 += fmaxf(fmaf(v1, sc1, sh1), 0.f);
    }
    float invc = 1.f / fmaxf((float)(r1 - r0), 1.f);
    float2 o; o.x = s0 * invc; o.y = s1 * invc;
    *(float2*)&z[(size_t)g * 160 + c0] = o;
    if (lane < 16) {
        float2 gv = *(const float2*)&gf[(size_t)g * 32 + lane * 2];
        *(float2*)&z[(size_t)g * 160 + 128 + lane * 2] = gv;
    }
}

// ================= MLP head ==================================================
__global__ __launch_bounds__(256) void k_mlp(const float* __restrict__ z,
                                             const float* __restrict__ W1,
                                             const float* __restrict__ b1,
                                             const float* __restrict__ W2,
                                             const float* __restrict__ b2,
                                             float* __restrict__ out) {
    __shared__ float zs[160];
    __shared__ float red[4];
    int g = blockIdx.x;
    int t = threadIdx.x;
    if (t < 160) zs[t] = z[(size_t)g * 160 + t];
    __syncthreads();
    float acc = b1[t];
#pragma unroll 8
    for (int i = 0; i < 160; i++) acc = fmaf(zs[i], W1[i * 256 + t], acc);
    acc = fmaxf(acc, 0.f);
    float part = acc * W2[t];
    part += __shfl_xor(part, 32, 64);
    part += __shfl_xor(part, 16, 64);
    part += __shfl_xor(part, 8, 64);
    part += __shfl_xor(part, 4, 64);
    part += __shfl_xor(part, 2, 64);
    part += __shfl_xor(part, 1, 64);
    if ((t & 63) == 0) red[t >> 6] = part;
    __syncthreads();
    if (t == 0) out[g] = red[0] + red[1] + red[2] + red[3] + b2[0];
}

extern "C" void kernel_launch(void* const* d_in, const int* in_sizes, int n_in,
                              void* d_out, int out_size, void* d_ws, size_t ws_size,
                              hipStream_t stream) {
    (void)in_sizes; (void)n_in; (void)out_size; (void)ws_size;

    const float* x     = (const float*)d_in[0];
    const int*   ei    = (const int*)d_in[1];
    const int*   batch = (const int*)d_in[2];
    const float* gf    = (const float*)d_in[3];
    const float* Wl1 = (const float*)d_in[4];
    const float* bl1 = (const float*)d_in[5];
    const float* Wr1 = (const float*)d_in[6];
    const float* br1 = (const float*)d_in[7];
    const float* att1  = (const float*)d_in[8];
    const float* bias1 = (const float*)d_in[9];
    const float* g1  = (const float*)d_in[10];
    const float* be1 = (const float*)d_in[11];
    const float* Wl2 = (const float*)d_in[12];
    const float* bl2 = (const float*)d_in[13];
    const float* Wr2 = (const float*)d_in[14];
    const float* br2 = (const float*)d_in[15];
    const float* att2  = (const float*)d_in[16];
    const float* bias2 = (const float*)d_in[17];
    const float* g2  = (const float*)d_in[18];
    const float* be2 = (const float*)d_in[19];
    const float* Wfc1 = (const float*)d_in[20];
    const float* bfc1 = (const float*)d_in[21];
    const float* Wfc2 = (const float*)d_in[22];
    const float* bfc2 = (const float*)d_in[23];
    float* out = (float*)d_out;

    char* ws = (char*)d_ws;
    unsigned short* xl = (unsigned short*)(ws + 0);            // 25.6 MB bf16
    unsigned short* xr = (unsigned short*)(ws + 25600000);     // 25.6 MB bf16
    unsigned* h     = (unsigned*)(ws + 51200000);              // 25.6 MB bf16 packed
    int*   colA     = (int*)(ws + 102400000);                  // 6.8 MB (byte offsets)
    int2*  bktBuf   = (int2*)(ws + 109200000);                 // 19.27 MB
    int*   bucketCur= (int*)(ws + 128467584);                  // 1 KB   } zeroed
    float* bnsum    = (float*)(ws + 128468608);                // 2 KB   } together
    int*   cnt      = (int*)(ws + 128470656);                  // 400 KB
    int*   startA   = (int*)(ws + 128871040);                  // 400 KB (100001)
    int*   bsum     = (int*)(ws + 129271168);
    int*   bbase    = (int*)(ws + 129272960);
    float* scsh     = (float*)(ws + 129274752);                // sc1|sh1|sc2|sh2
    int*   gstart   = (int*)(ws + 129276800);
    float* z        = (float*)(ws + 129281152);
    unsigned short* Wimg = (unsigned short*)(ws + 129936512);  // 64 KB

    // zero: bucketCur (1024) + bnsum (2048) — contiguous
    hipMemsetAsync(bucketCur, 0, 1024 + 2048, stream);

    // CSR build (shared by both layers) + graph boundaries
    k_part<<<(EP + 4095) / 4096, 256, 0, stream>>>(ei, bucketCur, bktBuf);
    k_gstart<<<(N_NODES + 255) / 256, 256, 0, stream>>>(batch, gstart);
    k_build_a<<<NB, 256, 0, stream>>>(bktBuf, bucketCur, cnt);
    k_s1<<<391, 256, 0, stream>>>(cnt, bsum);
    k_s2<<<1, 512, 0, stream>>>(bsum, bbase, startA);
    k_s3<<<391, 256, 0, stream>>>(cnt, bbase, startA);
    k_build_b<<<NB, 256, 0, stream>>>(bktBuf, bucketCur, startA, colA);

    int gemm_grid = (N_NODES + 63) / 64;

    // Layer 1
    k_wconv<<<16, 256, 0, stream>>>(Wl1, Wr1, Wimg);
    k_gemm<false, false><<<gemm_grid, 256, 0, stream>>>(x, Wimg, bl1, br1,
                                                        nullptr, nullptr, xl, xr, N_NODES);
    k_agg<<<GRID_AGG, 256, 0, stream>>>((const unsigned*)xl, (const unsigned*)xr,
                                        startA, (const unsigned*)colA, att1, bias1,
                                        h, bnsum + 0, bnsum + 128);
    k_bnfinal<<<1, 128, 0, stream>>>(bnsum + 0, bnsum + 128, g1, be1, scsh + 0, scsh + 128);

    // Layer 2 (BN1 apply + ReLU fused into GEMM A-staging, bf16 input)
    k_wconv<<<16, 256, 0, stream>>>(Wl2, Wr2, Wimg);
    k_gemm<true, true><<<gemm_grid, 256, 0, stream>>>(h, Wimg, bl2, br2,
                                                      scsh + 0, scsh + 128, xl, xr, N_NODES);
    k_agg<<<GRID_AGG, 256, 0, stream>>>((const unsigned*)xl, (const unsigned*)xr,
                                        startA, (const unsigned*)colA, att2, bias2,
                                        h, bnsum + 256, bnsum + 384);
    k_bnfinal<<<1, 128, 0, stream>>>(bnsum + 256, bnsum + 384, g2, be2, scsh + 256, scsh + 384);

    // Pool (BN2 apply + ReLU fused) + MLP
    k_pool<<<(NG + 3) / 4, 256, 0, stream>>>(h, gstart, gf, scsh + 256, scsh + 384, z);
    k_mlp<<<NG, 256, 0, stream>>>(z, Wfc1, bfc1, Wfc2, bfc2, out);
}

// Round 6
// 412.671 us; speedup vs baseline: 1.3031x; 1.3031x over previous
//
#include <hip/hip_runtime.h>

#define N_NODES 100000
#define E_EDGES 1600000
#define EP (E_EDGES + N_NODES)
#define NG 1024
#define NEG 0.2f
#define EPS_BN 1e-5f

#define NB 196        // dst buckets of 512 nodes
#define BCAP 12288    // per-bucket capacity

typedef __attribute__((ext_vector_type(8))) short bf8_t;
typedef __attribute__((ext_vector_type(4))) float f4_t;

__device__ __forceinline__ unsigned short f2b(float f) {   // f32 -> bf16 RNE
    unsigned u = __float_as_uint(f);
    u += 0x7FFF + ((u >> 16) & 1);
    return (unsigned short)(u >> 16);
}

// 16-lane sum via mov_dpp row_ror butterfly (schedulable intrinsics; compiler
// inserts DPP hazard nops). Result broadcast to all 16 lanes of each row.
__device__ __forceinline__ float rsum16(float p) {
    p += __int_as_float(__builtin_amdgcn_mov_dpp(__float_as_int(p), 0x128, 0xf, 0xf, true));
    p += __int_as_float(__builtin_amdgcn_mov_dpp(__float_as_int(p), 0x124, 0xf, 0xf, true));
    p += __int_as_float(__builtin_amdgcn_mov_dpp(__float_as_int(p), 0x122, 0xf, 0xf, true));
    p += __int_as_float(__builtin_amdgcn_mov_dpp(__float_as_int(p), 0x121, 0xf, 0xf, true));
    return p;
}

// ================= CSR build: partition -> histogram -> scan -> place =======
__global__ __launch_bounds__(256) void k_part(const int* __restrict__ ei,
                                              int* __restrict__ bucketCur,
                                              int2* __restrict__ buf) {
    __shared__ int lh[NB], lb[NB];
    int t = threadIdx.x;
    for (int i = t; i < NB; i += 256) lh[i] = 0;
    __syncthreads();
    int base = blockIdx.x * 4096;
    int2 e[16];
    int rk[16];
#pragma unroll
    for (int i = 0; i < 16; i++) {
        int idx = base + i * 256 + t;
        int s, d;
        if (idx < E_EDGES) { s = ei[idx]; d = ei[E_EDGES + idx]; }
        else if (idx < EP) { s = d = idx - E_EDGES; }
        else { s = -1; d = -1; }
        e[i].x = s; e[i].y = d;
        rk[i] = (d >= 0) ? atomicAdd(&lh[d >> 9], 1) : 0;
    }
    __syncthreads();
    for (int i = t; i < NB; i += 256) lb[i] = atomicAdd(&bucketCur[i], lh[i]);
    __syncthreads();
#pragma unroll
    for (int i = 0; i < 16; i++) {
        int d = e[i].y;
        if (d >= 0) {
            int bkt = d >> 9;
            buf[(size_t)bkt * BCAP + lb[bkt] + rk[i]] = e[i];
        }
    }
}

__global__ __launch_bounds__(256) void k_build_a(const int2* __restrict__ buf,
                                                 const int* __restrict__ bcnt,
                                                 int* __restrict__ cnt) {
    __shared__ int h[512];
    int b = blockIdx.x, t = threadIdx.x;
    for (int i = t; i < 512; i += 256) h[i] = 0;
    __syncthreads();
    int n = bcnt[b];
    const int2* p = buf + (size_t)b * BCAP;
    for (int i = t; i < n; i += 256) atomicAdd(&h[p[i].y & 511], 1);
    __syncthreads();
    int base = b << 9;
    for (int i = t; i < 512; i += 256) {
        int d = base + i;
        if (d < N_NODES) cnt[d] = h[i];
    }
}

__global__ __launch_bounds__(256) void k_s1(const int* __restrict__ cnt,
                                            int* __restrict__ bsum) {
    int b = blockIdx.x, t = threadIdx.x;
    int idx = b * 256 + t;
    int v = (idx < N_NODES) ? cnt[idx] : 0;
#pragma unroll
    for (int o = 1; o < 64; o <<= 1) v += __shfl_xor(v, o, 64);
    __shared__ int ws[4];
    if ((t & 63) == 0) ws[t >> 6] = v;
    __syncthreads();
    if (t == 0) bsum[b] = ws[0] + ws[1] + ws[2] + ws[3];
}

__global__ __launch_bounds__(512) void k_s2(const int* __restrict__ bsum,
                                            int* __restrict__ bbase,
                                            int* __restrict__ startA) {
    __shared__ int s[512];
    int t = threadIdx.x;
    int v = (t < 391) ? bsum[t] : 0;
    s[t] = v;
    __syncthreads();
    for (int o = 1; o < 512; o <<= 1) {
        int u = (t >= o) ? s[t - o] : 0;
        __syncthreads();
        s[t] += u;
        __syncthreads();
    }
    if (t < 391) bbase[t] = s[t] - v;   // exclusive
    if (t == 0) startA[N_NODES] = EP;
}

__global__ __launch_bounds__(256) void k_s3(const int* __restrict__ cnt,
                                            const int* __restrict__ bbase,
                                            int* __restrict__ startA) {
    __shared__ int s[256];
    int b = blockIdx.x, t = threadIdx.x;
    int idx = b * 256 + t;
    int v = (idx < N_NODES) ? cnt[idx] : 0;
    s[t] = v;
    __syncthreads();
    for (int o = 1; o < 256; o <<= 1) {
        int u = (t >= o) ? s[t - o] : 0;
        __syncthreads();
        s[t] += u;
        __syncthreads();
    }
    if (idx < N_NODES) startA[idx] = bbase[b] + s[t] - v;
}

// colA entries stored as BYTE offsets (src * 256) for saddr-form gathers.
__global__ __launch_bounds__(256) void k_build_b(const int2* __restrict__ buf,
                                                 const int* __restrict__ bcnt,
                                                 const int* __restrict__ startA,
                                                 int* __restrict__ colA) {
    __shared__ int h[512];
    int b = blockIdx.x, t = threadIdx.x;
    for (int i = t; i < 512; i += 256) h[i] = 0;
    __syncthreads();
    int n = bcnt[b];
    const int2* p = buf + (size_t)b * BCAP;
    for (int i = t; i < n; i += 256) {
        int2 e = p[i];
        int r = atomicAdd(&h[e.y & 511], 1);
        colA[startA[e.y] + r] = e.x << 8;
    }
}

// ================= W preconvert: f32 [k][n] -> bf16 swizzled LDS image ======
__global__ void k_wconv(const float* __restrict__ Wl, const float* __restrict__ Wr,
                        unsigned short* __restrict__ img) {
    int g = blockIdx.x * 256 + threadIdx.x;   // 4096 chunks
    int m = g >> 11, n = (g >> 4) & 127, kb = g & 15;
    const float* W = m ? Wr : Wl;
    unsigned short v[8];
#pragma unroll
    for (int j = 0; j < 8; j++) v[j] = f2b(W[(kb * 8 + j) * 128 + n]);
    int off = ((n * 256 + kb * 16) ^ ((n & 7) << 4)) + m * 32768;
    *(int4*)((char*)img + off) = *(int4*)v;
}

// ================= MFMA dual GEMM: xl = A@Wl + bl, xr = A@Wr + br (bf16) =====
template<bool AFF, bool BF16IN>
__global__ __launch_bounds__(256) void k_gemm(
    const void* __restrict__ Ain, const unsigned short* __restrict__ Wimg,
    const float* __restrict__ bl, const float* __restrict__ br,
    const float* __restrict__ sc, const float* __restrict__ sh,
    unsigned short* __restrict__ xl, unsigned short* __restrict__ xr, int M)
{
    __shared__ char lds[81920];
    short* As = (short*)lds;             // 16384 B
    short* Wt = (short*)(lds + 16384);   // 65536 B

    int t = threadIdx.x;
    int lane = t & 63;
    int w = t >> 6;
    int brow = blockIdx.x * 64;

    // ---- stage W: linear 64KB copy (image pre-swizzled by k_wconv) ----
    {
        const int4* src = (const int4*)Wimg;
        int4* dst = (int4*)Wt;
#pragma unroll
        for (int r = 0; r < 16; ++r) dst[r * 256 + t] = src[r * 256 + t];
    }

    // ---- stage A (f32 or packed-bf16 input; optional BN-affine+relu) ----
    {
        int kbase = (t & 7) * 16;
        float scv[16], shv[16];
        if (AFF) {
#pragma unroll
            for (int q = 0; q < 4; ++q) {
                float4 a4 = *(const float4*)&sc[kbase + q * 4];
                float4 b4 = *(const float4*)&sh[kbase + q * 4];
                scv[q*4+0]=a4.x; scv[q*4+1]=a4.y; scv[q*4+2]=a4.z; scv[q*4+3]=a4.w;
                shv[q*4+0]=b4.x; shv[q*4+1]=b4.y; shv[q*4+2]=b4.z; shv[q*4+3]=b4.w;
            }
        }
#pragma unroll
        for (int p = 0; p < 2; ++p) {
            int row = p * 32 + (t >> 3);
            int ar = brow + row; if (ar >= M) ar = M - 1;
            unsigned short vb[16];
            if (BF16IN) {
                const unsigned* src = (const unsigned*)Ain + (size_t)ar * 64 + (kbase >> 1);
                int4 r0 = *(const int4*)src;
                int4 r1 = *(const int4*)(src + 4);
                unsigned ua[8] = {(unsigned)r0.x,(unsigned)r0.y,(unsigned)r0.z,(unsigned)r0.w,
                                  (unsigned)r1.x,(unsigned)r1.y,(unsigned)r1.z,(unsigned)r1.w};
#pragma unroll
                for (int m = 0; m < 8; ++m) {
                    float f0 = __uint_as_float(ua[m] << 16);
                    float f1 = __uint_as_float(ua[m] & 0xFFFF0000u);
                    if (AFF) {
                        f0 = fmaxf(fmaf(f0, scv[2*m], shv[2*m]), 0.f);
                        f1 = fmaxf(fmaf(f1, scv[2*m+1], shv[2*m+1]), 0.f);
                    }
                    vb[2*m] = f2b(f0); vb[2*m+1] = f2b(f1);
                }
            } else {
                const float* src = (const float*)Ain + (size_t)ar * 128 + kbase;
#pragma unroll
                for (int q = 0; q < 4; ++q) {
                    float4 x4 = *(const float4*)&src[q * 4];
                    float vv[4] = {x4.x, x4.y, x4.z, x4.w};
#pragma unroll
                    for (int e = 0; e < 4; ++e) {
                        float f = vv[e];
                        if (AFF) f = fmaxf(fmaf(f, scv[q*4+e], shv[q*4+e]), 0.f);
                        vb[q * 4 + e] = f2b(f);
                    }
                }
            }
            int swz = (row & 7) << 4;
#pragma unroll
            for (int u = 0; u < 2; ++u) {
                int off = (row * 256 + kbase * 2 + u * 16) ^ swz;
                *(int4*)((char*)As + off) = *(int4*)&vb[u * 8];
            }
        }
    }
    __syncthreads();

    // ---- compute ----
    int rl = lane & 15;
    int kh = lane >> 4;
    int mat = w >> 1;
    int c0 = (w & 1) * 64;
    int swz = (rl & 7) << 4;

    f4_t acc[4][4];
#pragma unroll
    for (int i = 0; i < 4; ++i)
#pragma unroll
        for (int j = 0; j < 4; ++j) { f4_t z = {0.f,0.f,0.f,0.f}; acc[i][j] = z; }

    const char* Asc = (const char*)As;
    const char* Wtc = (const char*)Wt + mat * 32768;

#pragma unroll
    for (int s = 0; s < 4; ++s) {
        int kb2 = (s * 32 + kh * 8) * 2;
        bf8_t af[4], bfr[4];
#pragma unroll
        for (int i = 0; i < 4; ++i) {
            int row = 16 * i + rl;
            af[i] = *(const bf8_t*)(Asc + ((row * 256 + kb2) ^ swz));
        }
#pragma unroll
        for (int j = 0; j < 4; ++j) {
            int n = c0 + 16 * j + rl;
            bfr[j] = *(const bf8_t*)(Wtc + ((n * 256 + kb2) ^ swz));
        }
#pragma unroll
        for (int i = 0; i < 4; ++i)
#pragma unroll
            for (int j = 0; j < 4; ++j)
                acc[i][j] = __builtin_amdgcn_mfma_f32_16x16x32_bf16(af[i], bfr[j], acc[i][j], 0, 0, 0);
    }

    // ---- epilogue: bias + bf16, bounce through LDS for coalesced stores ----
    __syncthreads();
    short* Cs = (short*)lds;   // [64][256] bf16, swizzled
    const float* bb = mat ? br : bl;
    float blv[4];
#pragma unroll
    for (int j = 0; j < 4; ++j) blv[j] = bb[c0 + 16 * j + rl];
    int colbase = mat * 128 + c0;
#pragma unroll
    for (int i = 0; i < 4; ++i)
#pragma unroll
        for (int j = 0; j < 4; ++j) {
            int col = colbase + 16 * j + rl;
#pragma unroll
            for (int q = 0; q < 4; ++q) {
                int row = 16 * i + kh * 4 + q;
                int off = (row * 512 + col * 2) ^ ((row & 7) << 4);
                *(short*)((char*)Cs + off) = (short)f2b(acc[i][j][q] + blv[j]);
            }
        }
    __syncthreads();
#pragma unroll
    for (int rep = 0; rep < 8; ++rep) {
        int unit = rep * 256 + t;
        int row = unit >> 5;
        int slot = unit & 31;
        int gr = brow + row;
        if (gr < M) {
            int off = (row * 512 + slot * 16) ^ ((row & 7) << 4);
            int4 vv = *(const int4*)((char*)Cs + off);
            unsigned short* O = (slot < 16) ? xl : xr;
            int gcol = (slot & 15) * 8;
            *(int4*)&O[(size_t)gr * 128 + gcol] = vv;
        }
    }
}

// ===== fused edge softmax + aggregation: wave per dst node, 4-edge blocks ====
// Scalar (SGPR) loop control via readfirstlane; per-edge src offset via
// v_readlane -> saddr global_load; 16-lane reduce via mov_dpp butterfly.
__global__ __launch_bounds__(256) void k_agg(
    const unsigned* __restrict__ xl, const unsigned* __restrict__ xr,
    const int* __restrict__ startA, const unsigned* __restrict__ colB,
    const float* __restrict__ att, const float* __restrict__ bias,
    unsigned* __restrict__ hout)
{
    int tid = threadIdx.x;
    int lane = tid & 63;
    int n = __builtin_amdgcn_readfirstlane(blockIdx.x * 4 + (tid >> 6));
    if (n >= N_NODES) return;
    int c0 = lane * 2;

    float att0 = att[c0], att1 = att[c0 + 1];
    unsigned uxr = xr[(size_t)n * 64 + lane];
    float xr0 = __uint_as_float(uxr << 16);
    float xr1 = __uint_as_float(uxr & 0xFFFF0000u);
    int a0 = startA[n];
    int cn = startA[n + 1] - a0;   // >= 1 (self loop)
    const char* xlb = (const char*)xl;
    unsigned lane4 = (unsigned)lane * 4u;

    unsigned myS = colB[a0 + lane];          // colB padded by 64 ints
    unsigned off0 = (unsigned)__builtin_amdgcn_readlane((int)myS, 0);
#define RL(J)  ((unsigned)__builtin_amdgcn_readlane((int)myS, (J)))
#define GA(O)  (*(const unsigned*)(xlb + (O) + lane4))

    unsigned o;
    unsigned cA = GA(off0);
    o = (1 < cn) ? RL(1) : off0;  unsigned cB = GA(o);
    o = (2 < cn) ? RL(2) : off0;  unsigned cC = GA(o);
    o = (3 < cn) ? RL(3) : off0;  unsigned cD = GA(o);
    o = (4 < cn) ? RL(4) : off0;  unsigned cE = GA(o);
    o = (5 < cn) ? RL(5) : off0;  unsigned cF = GA(o);
    o = (6 < cn) ? RL(6) : off0;  unsigned cG = GA(o);
    o = (7 < cn) ? RL(7) : off0;  unsigned cH = GA(o);

    float acc0 = 0.f, acc1 = 0.f, wsum = 0.f;
    int nb = (cn + 3) >> 2;
#pragma unroll 2
    for (int b = 0; b < nb; ++b) {
        int jb = b * 4;
        int jn = jb + 8;
        unsigned pA = cA, pB = cA, pC = cA, pD = cA;
        if (jn < cn) {                        // wave-uniform branch
            if ((jn & 63) == 0) myS = colB[a0 + jn + lane];
            unsigned q0 = RL(jn & 63);
            unsigned q1 = (jn + 1 < cn) ? RL((jn + 1) & 63) : off0;
            unsigned q2 = (jn + 2 < cn) ? RL((jn + 2) & 63) : off0;
            unsigned q3 = (jn + 3 < cn) ? RL((jn + 3) & 63) : off0;
            pA = GA(q0); pB = GA(q1); pC = GA(q2); pD = GA(q3);
        }
        // compute 4 edges (independent chains -> ILP across DPP/exp)
        float v0a = __uint_as_float(cA << 16), v1a = __uint_as_float(cA & 0xFFFF0000u);
        float v0b = __uint_as_float(cB << 16), v1b = __uint_as_float(cB & 0xFFFF0000u);
        float v0c = __uint_as_float(cC << 16), v1c = __uint_as_float(cC & 0xFFFF0000u);
        float v0d = __uint_as_float(cD << 16), v1d = __uint_as_float(cD & 0xFFFF0000u);
        float e0, e1, pa, pb, pc, pd;
        e0 = v0a + xr0; e1 = v1a + xr1;
        e0 = fmaxf(e0, 0.2f * e0); e1 = fmaxf(e1, 0.2f * e1);
        pa = fmaf(e0, att0, e1 * att1);
        e0 = v0b + xr0; e1 = v1b + xr1;
        e0 = fmaxf(e0, 0.2f * e0); e1 = fmaxf(e1, 0.2f * e1);
        pb = fmaf(e0, att0, e1 * att1);
        e0 = v0c + xr0; e1 = v1c + xr1;
        e0 = fmaxf(e0, 0.2f * e0); e1 = fmaxf(e1, 0.2f * e1);
        pc = fmaf(e0, att0, e1 * att1);
        e0 = v0d + xr0; e1 = v1d + xr1;
        e0 = fmaxf(e0, 0.2f * e0); e1 = fmaxf(e1, 0.2f * e1);
        pd = fmaf(e0, att0, e1 * att1);

        pa = rsum16(pa); pb = rsum16(pb); pc = rsum16(pc); pd = rsum16(pd);

        float wa = __expf(pa);
        float wb = (jb + 1 < cn) ? __expf(pb) : 0.f;
        float wc = (jb + 2 < cn) ? __expf(pc) : 0.f;
        float wd = (jb + 3 < cn) ? __expf(pd) : 0.f;

        acc0 = fmaf(wa, v0a, acc0); acc1 = fmaf(wa, v1a, acc1);
        acc0 = fmaf(wb, v0b, acc0); acc1 = fmaf(wb, v1b, acc1);
        acc0 = fmaf(wc, v0c, acc0); acc1 = fmaf(wc, v1c, acc1);
        acc0 = fmaf(wd, v0d, acc0); acc1 = fmaf(wd, v1d, acc1);
        wsum += (wa + wb) + (wc + wd);

        cA = cE; cB = cF; cC = cG; cD = cH;
        cE = pA; cF = pB; cG = pC; cH = pD;
    }
#undef RL
#undef GA
    float inv = 1.f / wsum;
    float o0 = fmaf(acc0, inv, bias[c0]);
    float o1 = fmaf(acc1, inv, bias[c0 + 1]);
    hout[(size_t)n * 64 + lane] = (unsigned)f2b(o0) | ((unsigned)f2b(o1) << 16);
}

// ================= BatchNorm stats (bf16 h) + finalize =======================
__global__ __launch_bounds__(256) void k_bnstats(const unsigned* __restrict__ h,
                                                 float* __restrict__ gsum,
                                                 float* __restrict__ gsq) {
    int t = threadIdx.x;
    int col = t & 63;
    int wv = t >> 6;
    float s0 = 0.f, s1 = 0.f, q0 = 0.f, q1 = 0.f;
    for (int r = blockIdx.x * 4 + wv; r < N_NODES; r += 512 * 4) {
        unsigned u = h[(size_t)r * 64 + col];
        float v0 = __uint_as_float(u << 16);
        float v1 = __uint_as_float(u & 0xFFFF0000u);
        s0 += v0; q0 = fmaf(v0, v0, q0);
        s1 += v1; q1 = fmaf(v1, v1, q1);
    }
    __shared__ float2 sS[4][64], sQ[4][64];
    sS[wv][col] = make_float2(s0, s1);
    sQ[wv][col] = make_float2(q0, q1);
    __syncthreads();
    if (t < 64) {
        float2 a0 = sS[0][t], a1 = sS[1][t], a2 = sS[2][t], a3 = sS[3][t];
        float2 b0 = sQ[0][t], b1 = sQ[1][t], b2 = sQ[2][t], b3 = sQ[3][t];
        atomicAdd(&gsum[2 * t],     a0.x + a1.x + a2.x + a3.x);
        atomicAdd(&gsum[2 * t + 1], a0.y + a1.y + a2.y + a3.y);
        atomicAdd(&gsq[2 * t],      b0.x + b1.x + b2.x + b3.x);
        atomicAdd(&gsq[2 * t + 1],  b0.y + b1.y + b2.y + b3.y);
    }
}

__global__ void k_bnfinal(const float* __restrict__ gsum, const float* __restrict__ gsq,
                          const float* __restrict__ g, const float* __restrict__ be,
                          float* __restrict__ sc, float* __restrict__ sh) {
    int c = threadIdx.x;   // 128
    float mu = gsum[c] * (1.f / N_NODES);
    float var = gsq[c] * (1.f / N_NODES) - mu * mu;
    float s = rsqrtf(var + EPS_BN) * g[c];
    sc[c] = s;
    sh[c] = be[c] - mu * s;
}

// ================= graph boundaries (batch is sorted) ========================
__global__ void k_gstart(const int* __restrict__ batch, int* __restrict__ gstart) {
    int i = blockIdx.x * 256 + threadIdx.x;
    if (i >= N_NODES) return;
    int b = batch[i];
    int prev = (i == 0) ? -1 : batch[i - 1];
    for (int g = prev + 1; g <= b; g++) gstart[g] = i;
    if (i == N_NODES - 1)
        for (int g = b + 1; g <= NG; g++) gstart[g] = N_NODES;
}

// ====== mean pool over bf16 h (fused BN2 affine+relu) + concat global =======
__global__ __launch_bounds__(256) void k_pool(const unsigned* __restrict__ h,
                                              const int* __restrict__ gstart,
                                              const float* __restrict__ gf,
                                              const float* __restrict__ sc,
                                              const float* __restrict__ sh,
                                              float* __restrict__ z) {
    int wave = threadIdx.x >> 6;
    int lane = threadIdx.x & 63;
    int g = blockIdx.x * 4 + wave;
    if (g >= NG) return;
    int c0 = lane * 2;
    float sc0 = sc[c0], sc1 = sc[c0 + 1], sh0 = sh[c0], sh1 = sh[c0 + 1];
    int r0 = gstart[g], r1 = gstart[g + 1];
    float s0 = 0.f, s1 = 0.f;
    for (int r = r0; r < r1; r++) {
        unsigned u = h[(size_t)r * 64 + lane];
        float v0 = __uint_as_float(u << 16);
        float v1 = __uint_as_float(u & 0xFFFF0000u);
        s0 += fmaxf(fmaf(v0, sc0, sh0), 0.f);
        s1 += fmaxf(fmaf(v1, sc1, sh1), 0.f);
    }
    float invc = 1.f / fmaxf((float)(r1 - r0), 1.f);
    float2 o; o.x = s0 * invc; o.y = s1 * invc;
    *(float2*)&z[(size_t)g * 160 + c0] = o;
    if (lane < 16) {
        float2 gv = *(const float2*)&gf[(size_t)g * 32 + lane * 2];
        *(float2*)&z[(size_t)g * 160 + 128 + lane * 2] = gv;
    }
}

// ================= MLP head ==================================================
__global__ __launch_bounds__(256) void k_mlp(const float* __restrict__ z,
                                             const float* __restrict__ W1,
                                             const float* __restrict__ b1,
                                             const float* __restrict__ W2,
                                             const float* __restrict__ b2,
                                             float* __restrict__ out) {
    __shared__ float zs[160];
    __shared__ float red[4];
    int g = blockIdx.x;
    int t = threadIdx.x;
    if (t < 160) zs[t] = z[(size_t)g * 160 + t];
    __syncthreads();
    float acc = b1[t];
#pragma unroll 8
    for (int i = 0; i < 160; i++) acc = fmaf(zs[i], W1[i * 256 + t], acc);
    acc = fmaxf(acc, 0.f);
    float part = acc * W2[t];
    part += __shfl_xor(part, 32, 64);
    part += __shfl_xor(part, 16, 64);
    part += __shfl_xor(part, 8, 64);
    part += __shfl_xor(part, 4, 64);
    part += __shfl_xor(part, 2, 64);
    part += __shfl_xor(part, 1, 64);
    if ((t & 63) == 0) red[t >> 6] = part;
    __syncthreads();
    if (t == 0) out[g] = red[0] + red[1] + red[2] + red[3] + b2[0];
}

extern "C" void kernel_launch(void* const* d_in, const int* in_sizes, int n_in,
                              void* d_out, int out_size, void* d_ws, size_t ws_size,
                              hipStream_t stream) {
    (void)in_sizes; (void)n_in; (void)out_size; (void)ws_size;

    const float* x     = (const float*)d_in[0];
    const int*   ei    = (const int*)d_in[1];
    const int*   batch = (const int*)d_in[2];
    const float* gf    = (const float*)d_in[3];
    const float* Wl1 = (const float*)d_in[4];
    const float* bl1 = (const float*)d_in[5];
    const float* Wr1 = (const float*)d_in[6];
    const float* br1 = (const float*)d_in[7];
    const float* att1  = (const float*)d_in[8];
    const float* bias1 = (const float*)d_in[9];
    const float* g1  = (const float*)d_in[10];
    const float* be1 = (const float*)d_in[11];
    const float* Wl2 = (const float*)d_in[12];
    const float* bl2 = (const float*)d_in[13];
    const float* Wr2 = (const float*)d_in[14];
    const float* br2 = (const float*)d_in[15];
    const float* att2  = (const float*)d_in[16];
    const float* bias2 = (const float*)d_in[17];
    const float* g2  = (const float*)d_in[18];
    const float* be2 = (const float*)d_in[19];
    const float* Wfc1 = (const float*)d_in[20];
    const float* bfc1 = (const float*)d_in[21];
    const float* Wfc2 = (const float*)d_in[22];
    const float* bfc2 = (const float*)d_in[23];
    float* out = (float*)d_out;

    char* ws = (char*)d_ws;
    unsigned short* xl = (unsigned short*)(ws + 0);            // 25.6 MB bf16
    unsigned short* xr = (unsigned short*)(ws + 25600000);     // 25.6 MB bf16
    unsigned* h     = (unsigned*)(ws + 51200000);              // 25.6 MB bf16 packed
    int*   colA     = (int*)(ws + 76800000);                   // 6.8 MB + 256 B pad
    int2*  bktBuf   = (int2*)(ws + 83600384);                  // 19.27 MB
    int*   bucketCur= (int*)(ws + 102868224);                  // 1 KB   } zeroed
    float* bnsum    = (float*)(ws + 102869248);                // 2 KB   } together
    int*   cnt      = (int*)(ws + 102871296);                  // 400 KB
    int*   startA   = (int*)(ws + 103271296);                  // 400 KB (100001)
    int*   bsum     = (int*)(ws + 103671424);
    int*   bbase    = (int*)(ws + 103673472);
    float* scsh     = (float*)(ws + 103675520);                // sc1|sh1|sc2|sh2
    int*   gstart   = (int*)(ws + 103677568);
    float* z        = (float*)(ws + 103681920);
    unsigned short* Wimg = (unsigned short*)(ws + 104337280);  // 64 KB

    // zero: bucketCur (1024) + bnsum (2048) — contiguous
    hipMemsetAsync(bucketCur, 0, 1024 + 2048, stream);

    // CSR build (shared by both layers) + graph boundaries
    k_part<<<(EP + 4095) / 4096, 256, 0, stream>>>(ei, bucketCur, bktBuf);
    k_gstart<<<(N_NODES + 255) / 256, 256, 0, stream>>>(batch, gstart);
    k_build_a<<<NB, 256, 0, stream>>>(bktBuf, bucketCur, cnt);
    k_s1<<<391, 256, 0, stream>>>(cnt, bsum);
    k_s2<<<1, 512, 0, stream>>>(bsum, bbase, startA);
    k_s3<<<391, 256, 0, stream>>>(cnt, bbase, startA);
    k_build_b<<<NB, 256, 0, stream>>>(bktBuf, bucketCur, startA, colA);

    int gemm_grid = (N_NODES + 63) / 64;

    // Layer 1
    k_wconv<<<16, 256, 0, stream>>>(Wl1, Wr1, Wimg);
    k_gemm<false, false><<<gemm_grid, 256, 0, stream>>>(x, Wimg, bl1, br1,
                                                        nullptr, nullptr, xl, xr, N_NODES);
    k_agg<<<(N_NODES + 3) / 4, 256, 0, stream>>>((const unsigned*)xl, (const unsigned*)xr,
                                                 startA, (const unsigned*)colA, att1, bias1, h);
    k_bnstats<<<512, 256, 0, stream>>>(h, bnsum + 0, bnsum + 128);
    k_bnfinal<<<1, 128, 0, stream>>>(bnsum + 0, bnsum + 128, g1, be1, scsh + 0, scsh + 128);

    // Layer 2 (BN1 apply + ReLU fused into GEMM A-staging, bf16 input)
    k_wconv<<<16, 256, 0, stream>>>(Wl2, Wr2, Wimg);
    k_gemm<true, true><<<gemm_grid, 256, 0, stream>>>(h, Wimg, bl2, br2,
                                                      scsh + 0, scsh + 128, xl, xr, N_NODES);
    k_agg<<<(N_NODES + 3) / 4, 256, 0, stream>>>((const unsigned*)xl, (const unsigned*)xr,
                                                 startA, (const unsigned*)colA, att2, bias2, h);
    k_bnstats<<<512, 256, 0, stream>>>(h, bnsum + 256, bnsum + 384);
    k_bnfinal<<<1, 128, 0, stream>>>(bnsum + 256, bnsum + 384, g2, be2, scsh + 256, scsh + 384);

    // Pool (BN2 apply + ReLU fused) + MLP
    k_pool<<<(NG + 3) / 4, 256, 0, stream>>>(h, gstart, gf, scsh + 256, scsh + 384, z);
    k_mlp<<<NG, 256, 0, stream>>>(z, Wfc1, bfc1, Wfc2, bfc2, out);
}